// Round 3
// baseline (369.034 us; speedup 1.0000x reference)
//
#include <hip/hip_runtime.h>

#define TPB 256

namespace {
constexpr int B = 8, F = 6, NB = 5, NS = 7, H = 192, W = 192, C = 3;
constexpr int FM1 = F - 1;                 // frames 1..5
constexpr int HW = H * W;                  // 36864
constexpr int HW4 = HW / 4;                // 9216 float4 per plane
constexpr int PAIRS = B * FM1;             // 40
constexpr int BPP = HW4 / TPB;             // 36 blocks per pair
constexpr int GRID = PAIRS * BPP;          // 1440 blocks
constexpr int NSLOT = 64;
constexpr int SLOT_STRIDE = 16;            // 64 B apart
constexpr float EPS = 1e-7f;
constexpr float LN2 = 0.69314718055994530942f;
constexpr float K_BCE = LN2 / (float)HW;
constexpr float COEF = 0.1f / (float)C;
}

typedef float v4f __attribute__((ext_vector_type(4)));

__device__ __forceinline__ v4f ntload(const v4f* p) {
  return __builtin_nontemporal_load(p);   // single-use data: skip L1 alloc
}
__device__ __forceinline__ v4f step05(v4f v) {
  v4f r;
  r.x = v.x > 0.5f ? 1.f : 0.f; r.y = v.y > 0.5f ? 1.f : 0.f;
  r.z = v.z > 0.5f ? 1.f : 0.f; r.w = v.w > 0.5f ? 1.f : 0.f;
  return r;
}
__device__ __forceinline__ v4f clamp4(v4f p) {
  v4f r;
  r.x = __builtin_amdgcn_fmed3f(p.x, EPS, 1.0f - EPS);
  r.y = __builtin_amdgcn_fmed3f(p.y, EPS, 1.0f - EPS);
  r.z = __builtin_amdgcn_fmed3f(p.z, EPS, 1.0f - EPS);
  r.w = __builtin_amdgcn_fmed3f(p.w, EPS, 1.0f - EPS);
  return r;
}
__device__ __forceinline__ v4f log2_4(v4f p) {
  v4f r;
  r.x = __log2f(p.x); r.y = __log2f(p.y);
  r.z = __log2f(p.z); r.w = __log2f(p.w);
  return r;
}

__global__ __launch_bounds__(TPB) void em_rec_loss_kernel(
    const float* __restrict__ seg,    // [B,F,NB,H,W]
    const float* __restrict__ masks,  // [B,F,NS,H,W]
    const float* __restrict__ recon,  // [B,F,NB,C,H,W]
    const float* __restrict__ rtgt,   // [B,F,C,H,W]
    const float* __restrict__ vis,    // [B,F,NS,H,W]
    const float* __restrict__ attn,   // [B,F,NS,NB]
    float* __restrict__ partial,
    unsigned* __restrict__ ctr,
    float* __restrict__ out)
{
  const int blk = blockIdx.x;
  const int pair = blk / BPP;
  const int chunk = blk - pair * BPP;
  const int b = pair / FM1;
  const int f = pair - b * FM1 + 1;
  const int bf = b * F + f;

  // block-uniform raw attn weights (uniform address -> scalar loads)
  float a[NS][NB];
  const float* at = attn + (size_t)bf * NS * NB;
  #pragma unroll
  for (int s = 0; s < NS; ++s)
    #pragma unroll
    for (int n = 0; n < NB; ++n) a[s][n] = at[s * NB + n];
  float A[NB];
  #pragma unroll
  for (int n = 0; n < NB; ++n) {
    float t = 0.f;
    #pragma unroll
    for (int s = 0; s < NS; ++s) t += a[s][n];
    A[n] = t;
  }

  const v4f* sp = (const v4f*)(seg   + (size_t)bf * NB * HW);
  const v4f* mp = (const v4f*)(masks + (size_t)bf * NS * HW);
  const v4f* vp = (const v4f*)(vis   + (size_t)bf * NS * HW);
  const v4f* rp = (const v4f*)(recon + (size_t)bf * NB * C * HW);
  const v4f* tp = (const v4f*)(rtgt  + (size_t)bf * C * HW);

  // Per-pair phase rotation: every plane/chunk stride is a 4 KB multiple, so
  // without rotation ALL loads machine-wide share address bits [11:4] ->
  // instantaneous channel/L3-slice imbalance. rot = pair*231 float4s
  // (3696 B, not 4K-congruent) gives 40 distinct phases. Bijective on the
  // pair's pixels, so the sum is unchanged; coalescing intact except the
  // one seam wave per pair.
  const int rot = pair * 231;
  int q = chunk * TPB + threadIdx.x + rot;
  if (q >= HW4) q -= HW4;

  v4f m4[NS], v4[NS];
  #pragma unroll
  for (int s = 0; s < NS; ++s) m4[s] = ntload(&mp[s * HW4 + q]);
  #pragma unroll
  for (int s = 0; s < NS; ++s) v4[s] = ntload(&vp[s * HW4 + q]);

  // issue the rec-target stream before the wt/wv VALU chain so its VMEM
  // latency overlaps the step05/FMA work below
  v4f tg[C];
  #pragma unroll
  for (int c = 0; c < C; ++c) tg[c] = ntload(&tp[c * HW4 + q]);

  v4f wt[NB], wv[NB];
  #pragma unroll
  for (int n = 0; n < NB; ++n) { wt[n] = 0.f; wv[n] = 0.f; }
  #pragma unroll
  for (int s = 0; s < NS; ++s) {
    const v4f t4 = step05(m4[s]);
    const v4f vv = step05(v4[s]);
    #pragma unroll
    for (int n = 0; n < NB; ++n) {
      wt[n] += a[s][n] * t4;
      wv[n] += a[s][n] * vv;
    }
  }

  v4f accB = 0.f, accM = 0.f;
  #pragma unroll
  for (int n = 0; n < NB; ++n) {
    const v4f p  = clamp4(ntload(&sp[n * HW4 + q]));
    const v4f g  = log2_4(p);
    const v4f g1 = log2_4(1.0f - p);
    v4f d2 = 0.f;
    #pragma unroll
    for (int c = 0; c < C; ++c) {
      const v4f d = ntload(&rp[(n * C + c) * HW4 + q]) - tg[c];
      d2 += d * d;
    }
    accB += g1 * (wt[n] - A[n]) - g * wt[n];
    accM += d2 * wv[n];
  }

  const float sB = (accB.x + accB.y) + (accB.z + accB.w);
  const float sM = (accM.x + accM.y) + (accM.z + accM.w);
  float acc = fmaf(K_BCE, sB, COEF * sM);

  #pragma unroll
  for (int off = 32; off > 0; off >>= 1)
    acc += __shfl_down(acc, off, 64);

  __shared__ float wsum[TPB / 64];
  __shared__ int amLast;
  const int lane = threadIdx.x & 63;
  const int wid = threadIdx.x >> 6;
  if (lane == 0) wsum[wid] = acc;
  __syncthreads();
  if (threadIdx.x == 0) {
    float s = 0.f;
    #pragma unroll
    for (int i = 0; i < TPB / 64; ++i) s += wsum[i];
    atomicAdd(&partial[(blk & (NSLOT - 1)) * SLOT_STRIDE], s);
    // publish my slot update, then bump the done-counter (device scope)
    __threadfence();
    unsigned old = __hip_atomic_fetch_add(ctr, 1u, __ATOMIC_ACQ_REL,
                                          __HIP_MEMORY_SCOPE_AGENT);
    amLast = (old == (unsigned)(GRID - 1));
  }
  __syncthreads();

  // last block to finish folds the 64 slots and writes the scalar output.
  // AGENT-scope atomic loads read at the device-coherent point, past any
  // stale per-XCD L2 lines left by the zero-fill of `partial`.
  if (amLast && threadIdx.x < 64) {
    float v = __hip_atomic_load(&partial[threadIdx.x * SLOT_STRIDE],
                                __ATOMIC_RELAXED, __HIP_MEMORY_SCOPE_AGENT);
    #pragma unroll
    for (int off = 32; off > 0; off >>= 1)
      v += __shfl_down(v, off, 64);
    if (threadIdx.x == 0) {
      constexpr float SCALE = 20.0f / (float)(B * FM1 * NB * NS);
      out[0] = v * SCALE;
    }
  }
}

extern "C" void kernel_launch(void* const* d_in, const int* in_sizes, int n_in,
                              void* d_out, int out_size, void* d_ws, size_t ws_size,
                              hipStream_t stream) {
  const float* seg   = (const float*)d_in[0];
  const float* masks = (const float*)d_in[1];
  const float* recon = (const float*)d_in[2];
  const float* rtgt  = (const float*)d_in[3];
  const float* vis   = (const float*)d_in[4];
  const float* attn  = (const float*)d_in[5];

  float* out = (float*)d_out;
  float* partial = (float*)d_ws;
  unsigned* ctr = (unsigned*)((char*)d_ws + NSLOT * SLOT_STRIDE * sizeof(float));

  // zero the 64 accumulation slots + the completion counter (ws is poisoned
  // by the harness each iteration, so this init is mandatory)
  hipMemsetAsync(d_ws, 0, NSLOT * SLOT_STRIDE * sizeof(float) + 64, stream);

  em_rec_loss_kernel<<<GRID, TPB, 0, stream>>>(seg, masks, recon, rtgt, vis,
                                               attn, partial, ctr, out);
}